// Round 1
// baseline (1173.569 us; speedup 1.0000x reference)
//
#include <hip/hip_runtime.h>
#include <math.h>

// Problem constants
#define BB 4
#define DD 256
#define LL 2048
#define EE 512
#define NN 16
#define KK 7
#define RR 16
#define NC 8               // scan chunks
#define CLEN (LL / NC)     // 256 steps per chunk

// ---------------------------------------------------------------------------
// conv_ff: out[b][do][l] = relu(bias[do] + sum_{di,k} x[b][di][l+k-3] * w[do][di][k])
// grid (L/512, D/4, B), block 256. LDS-staged x tile, scalar-cached w.
// ---------------------------------------------------------------------------
__global__ __launch_bounds__(256) void k_conv_ff(const float* __restrict__ x,
                                                 const float* __restrict__ w,
                                                 const float* __restrict__ bias,
                                                 float* __restrict__ out) {
    __shared__ float xs[8][520];   // 8 di rows x (512+6) window
    const int tid = threadIdx.x;
    const int lt  = blockIdx.x * 512;
    const int do0 = blockIdx.y * 4;
    const int b   = blockIdx.z;
    float acc[4][2] = {};
    for (int di0 = 0; di0 < DD; di0 += 8) {
        __syncthreads();
        for (int i = tid; i < 8 * 518; i += 256) {
            int r = i / 518;
            int c = i - r * 518;
            int gl = lt + c - 3;
            xs[r][c] = (gl >= 0 && gl < LL) ? x[((size_t)(b * DD + di0 + r)) * LL + gl] : 0.f;
        }
        __syncthreads();
#pragma unroll
        for (int r = 0; r < 8; ++r) {
#pragma unroll
            for (int k = 0; k < KK; ++k) {
                float xv0 = xs[r][tid + k];
                float xv1 = xs[r][tid + 256 + k];
#pragma unroll
                for (int j = 0; j < 4; ++j) {
                    float wv = w[((size_t)(do0 + j) * DD + di0 + r) * KK + k];  // block-uniform -> s_load
                    acc[j][0] = fmaf(xv0, wv, acc[j][0]);
                    acc[j][1] = fmaf(xv1, wv, acc[j][1]);
                }
            }
        }
    }
#pragma unroll
    for (int j = 0; j < 4; ++j) {
        float bv = bias[do0 + j];
        float v0 = acc[j][0] + bv;
        float v1 = acc[j][1] + bv;
        size_t base = (size_t)(b * DD + do0 + j) * LL + lt;
        out[base + tid]       = v0 > 0.f ? v0 : 0.f;
        out[base + tid + 256] = v1 > 0.f ? v1 : 0.f;
    }
}

// ---------------------------------------------------------------------------
// instance norm over L per (b,d), fused * mask.  grid B*D blocks, 256 thr.
// ---------------------------------------------------------------------------
__global__ __launch_bounds__(256) void k_instnorm(const float* __restrict__ x,
                                                  const float* __restrict__ mask,
                                                  float* __restrict__ out) {
    const int bd = blockIdx.x;
    const int b = bd >> 8;   // D=256
    const int tid = threadIdx.x;
    const float* row = x + (size_t)bd * LL;
    float v[8];
    float s = 0.f, s2 = 0.f;
#pragma unroll
    for (int i = 0; i < 8; ++i) {
        v[i] = row[i * 256 + tid];
        s += v[i];
        s2 = fmaf(v[i], v[i], s2);
    }
#pragma unroll
    for (int off = 32; off > 0; off >>= 1) {
        s  += __shfl_down(s, off);
        s2 += __shfl_down(s2, off);
    }
    __shared__ float red[2][4];
    if ((tid & 63) == 0) { red[0][tid >> 6] = s; red[1][tid >> 6] = s2; }
    __syncthreads();
    s  = red[0][0] + red[0][1] + red[0][2] + red[0][3];
    s2 = red[1][0] + red[1][1] + red[1][2] + red[1][3];
    const float mu  = s * (1.f / LL);
    const float var = s2 * (1.f / LL) - mu * mu;
    const float inv = rsqrtf(var + 1e-5f);
    const float* mrow = mask + (size_t)b * LL;
    float* orow = out + (size_t)bd * LL;
#pragma unroll
    for (int i = 0; i < 8; ++i)
        orow[i * 256 + tid] = (v[i] - mu) * inv * mrow[i * 256 + tid];
}

// ---------------------------------------------------------------------------
// Generic fp32 GEMM: out[b][m][l] = act(bias[m] + sum_c W[m*C+c] * X[b*sXb + c*L + l])
// ACT: 0 = none, 1 = softplus.  grid (L/64, ceil(M/64), B), block 256.
// ---------------------------------------------------------------------------
template <int ACT>
__global__ __launch_bounds__(256) void k_gemm(const float* __restrict__ X,
                                              const float* __restrict__ W,
                                              const float* __restrict__ bias,
                                              float* __restrict__ out,
                                              int M, int C, long sXb, long sOb) {
    __shared__ float Ws[16][68];  // [c][m], pad 4 for conflict-free + 16B-aligned rows
    __shared__ float Xs[16][64];  // [c][l]
    const int tid = threadIdx.x;
    const int tx = tid & 15, ty = tid >> 4;
    const int l0 = blockIdx.x * 64, m0 = blockIdx.y * 64, b = blockIdx.z;
    float acc[4][4] = {};
    for (int c0 = 0; c0 < C; c0 += 16) {
        __syncthreads();
        {
            int i = tid;
#pragma unroll
            for (int it = 0; it < 4; ++it, i += 256) {
                int cc = i & 15, mm = i >> 4;
                int gm = m0 + mm;
                Ws[cc][mm] = (gm < M) ? W[(size_t)gm * C + c0 + cc] : 0.f;
                int ll = i & 63, c2 = i >> 6;
                Xs[c2][ll] = X[(size_t)b * sXb + (size_t)(c0 + c2) * LL + l0 + ll];
            }
        }
        __syncthreads();
#pragma unroll
        for (int c = 0; c < 16; ++c) {
            float4 av = *(const float4*)&Ws[c][ty * 4];
            float4 bv = *(const float4*)&Xs[c][tx * 4];
            float a[4] = {av.x, av.y, av.z, av.w};
            float x4[4] = {bv.x, bv.y, bv.z, bv.w};
#pragma unroll
            for (int i2 = 0; i2 < 4; ++i2)
#pragma unroll
                for (int j = 0; j < 4; ++j)
                    acc[i2][j] = fmaf(a[i2], x4[j], acc[i2][j]);
        }
    }
#pragma unroll
    for (int i2 = 0; i2 < 4; ++i2) {
        int m = m0 + ty * 4 + i2;
        if (m >= M) continue;
        float bv = bias ? bias[m] : 0.f;
        float4 r;
        float* rp = &r.x;
#pragma unroll
        for (int j = 0; j < 4; ++j) {
            float v = acc[i2][j] + bv;
            if (ACT == 1) v = fmaxf(v, 0.f) + log1pf(expf(-fabsf(v)));  // softplus (jax form)
            rp[j] = v;
        }
        *(float4*)&out[(size_t)b * sOb + (size_t)m * LL + l0 + tx * 4] = r;
    }
}

// ---------------------------------------------------------------------------
// Depthwise causal conv (K=7, pad 6 left) + silu.  xp = rows [0,E) of xz.
// grid (L/256, E, B), block 256.
// ---------------------------------------------------------------------------
__global__ __launch_bounds__(256) void k_dwconv(const float* __restrict__ xz,
                                                const float* __restrict__ cw,
                                                const float* __restrict__ cb,
                                                float* __restrict__ xc) {
    const int l = blockIdx.x * 256 + threadIdx.x;
    const int e = blockIdx.y;
    const int b = blockIdx.z;
    const float* row = xz + ((size_t)b * (2 * EE) + e) * LL;
    float wv[KK];
#pragma unroll
    for (int k = 0; k < KK; ++k) wv[k] = cw[e * KK + k];
    float acc = cb[e];
#pragma unroll
    for (int k = 0; k < KK; ++k) {
        int ll = l + k - (KK - 1);
        if (ll >= 0) acc = fmaf(row[ll], wv[k], acc);
    }
    float sig = 1.f / (1.f + expf(-acc));
    xc[((size_t)b * EE + e) * LL + l] = acc * sig;
}

// ---------------------------------------------------------------------------
// Selective scan, chunked linear recurrence.
// Thread map: t = ch*32768 + b*8192 + e*16 + n.
// Pass A: per-chunk local scan from h0=0; store aprod = prod(dA), hend.
// ---------------------------------------------------------------------------
__global__ __launch_bounds__(256) void k_scanA(const float* __restrict__ dt,
                                               const float* __restrict__ u,
                                               const float* __restrict__ xdbl,
                                               const float* __restrict__ A_log,
                                               float* __restrict__ aprod,
                                               float* __restrict__ hend) {
    const int t = blockIdx.x * 256 + threadIdx.x;
    const int n = t & 15;
    const int e = (t >> 4) & (EE - 1);
    const int b = (t >> 13) & (BB - 1);
    const int ch = t >> 15;
    const float Ae = -expf(A_log[e * NN + n]);
    const size_t rbe = (size_t)(b * EE + e) * LL + ch * CLEN;
    const float* dtp = dt + rbe;
    const float* up  = u + rbe;
    const float* Bp  = xdbl + ((size_t)(b * 48 + RR + n)) * LL + ch * CLEN;
    float h = 0.f, ap = 1.f;
    for (int i = 0; i < CLEN; i += 4) {
        float4 d4 = *(const float4*)(dtp + i);
        float4 u4 = *(const float4*)(up + i);
        float4 b4 = *(const float4*)(Bp + i);
        float dv[4] = {d4.x, d4.y, d4.z, d4.w};
        float uv[4] = {u4.x, u4.y, u4.z, u4.w};
        float bv[4] = {b4.x, b4.y, b4.z, b4.w};
#pragma unroll
        for (int j = 0; j < 4; ++j) {
            float dA = __expf(dv[j] * Ae);
            h = fmaf(dA, h, dv[j] * uv[j] * bv[j]);
            ap *= dA;
        }
    }
    aprod[t] = ap;
    hend[t] = h;
}

// Pass B: carry[ch] for each (b,e,n): carry[0]=0; carry[c]=aprod[c-1]*carry[c-1]+hend[c-1]
__global__ __launch_bounds__(256) void k_scanB(const float* __restrict__ aprod,
                                               const float* __restrict__ hend,
                                               float* __restrict__ carry) {
    const int t = blockIdx.x * 256 + threadIdx.x;  // 32768 threads = (b,e,n)
    float c = 0.f;
#pragma unroll
    for (int ch = 0; ch < NC; ++ch) {
        size_t idx = (size_t)ch * 32768 + t;
        carry[idx] = c;
        c = fmaf(aprod[idx], c, hend[idx]);
    }
}

// Pass C: re-scan with carry-in, y = (sum_n h*C + u*Dp) * silu(z)
__global__ __launch_bounds__(256) void k_scanC(const float* __restrict__ dt,
                                               const float* __restrict__ u,
                                               const float* __restrict__ xdbl,
                                               const float* __restrict__ A_log,
                                               const float* __restrict__ Dp,
                                               const float* __restrict__ xz,  // z = rows [E,2E)
                                               const float* __restrict__ carry,
                                               float* __restrict__ y) {
    const int t = blockIdx.x * 256 + threadIdx.x;
    const int n = t & 15;
    const int e = (t >> 4) & (EE - 1);
    const int b = (t >> 13) & (BB - 1);
    const int ch = t >> 15;
    const float Ae = -expf(A_log[e * NN + n]);
    const size_t rbe = (size_t)(b * EE + e) * LL + ch * CLEN;
    const float* dtp = dt + rbe;
    const float* up  = u + rbe;
    const float* Bp  = xdbl + ((size_t)(b * 48 + RR + n)) * LL + ch * CLEN;
    const float* Cp  = xdbl + ((size_t)(b * 48 + RR + NN + n)) * LL + ch * CLEN;
    const float* zp  = xz + ((size_t)b * (2 * EE) + EE + e) * LL + ch * CLEN;
    const float Dpe = Dp[e];
    float* yp = y + rbe;
    float h = carry[t];
    for (int i = 0; i < CLEN; i += 4) {
        float4 d4 = *(const float4*)(dtp + i);
        float4 u4 = *(const float4*)(up + i);
        float4 b4 = *(const float4*)(Bp + i);
        float4 c4 = *(const float4*)(Cp + i);
        float4 z4 = *(const float4*)(zp + i);
        float dv[4] = {d4.x, d4.y, d4.z, d4.w};
        float uv[4] = {u4.x, u4.y, u4.z, u4.w};
        float bv[4] = {b4.x, b4.y, b4.z, b4.w};
        float cv[4] = {c4.x, c4.y, c4.z, c4.w};
        float zv[4] = {z4.x, z4.y, z4.z, z4.w};
#pragma unroll
        for (int j = 0; j < 4; ++j) {
            float dA = __expf(dv[j] * Ae);
            h = fmaf(dA, h, dv[j] * uv[j] * bv[j]);
            float p = h * cv[j];
            p += __shfl_xor(p, 1);
            p += __shfl_xor(p, 2);
            p += __shfl_xor(p, 4);
            p += __shfl_xor(p, 8);
            if (n == 0) {
                float zz = zv[j];
                float sig = 1.f / (1.f + __expf(-zz));
                yp[i + j] = (p + uv[j] * Dpe) * (zz * sig);
            }
        }
    }
}

// ---------------------------------------------------------------------------
// final: out = (x + out0 + (s + c) * mask) * mask
// ---------------------------------------------------------------------------
__global__ __launch_bounds__(256) void k_final(const float* __restrict__ x,
                                               const float* __restrict__ out0,
                                               const float* __restrict__ sout,
                                               const float* __restrict__ cout,
                                               const float* __restrict__ mask,
                                               float* __restrict__ out) {
    const size_t idx = ((size_t)blockIdx.x * 256 + threadIdx.x) * 4;
    const size_t row = idx >> 11;    // / L
    const int b = (int)(row >> 8);   // / D
    const int l = (int)(idx & (LL - 1));
    float4 xv = *(const float4*)(x + idx);
    float4 o0 = *(const float4*)(out0 + idx);
    float4 sv = *(const float4*)(sout + idx);
    float4 cv = *(const float4*)(cout + idx);
    float4 mv = *(const float4*)(mask + (size_t)b * LL + l);
    float4 r;
    r.x = (xv.x + o0.x + (sv.x + cv.x) * mv.x) * mv.x;
    r.y = (xv.y + o0.y + (sv.y + cv.y) * mv.y) * mv.y;
    r.z = (xv.z + o0.z + (sv.z + cv.z) * mv.z) * mv.z;
    r.w = (xv.w + o0.w + (sv.w + cv.w) * mv.w) * mv.w;
    *(float4*)(out + idx) = r;
}

// ---------------------------------------------------------------------------
extern "C" void kernel_launch(void* const* d_in, const int* in_sizes, int n_in,
                              void* d_out, int out_size, void* d_ws, size_t ws_size,
                              hipStream_t stream) {
    const float* x    = (const float*)d_in[0];
    const float* enc  = (const float*)d_in[1];
    const float* mask = (const float*)d_in[2];
    const float* ff_w = (const float*)d_in[3];
    const float* ff_b = (const float*)d_in[4];
    const float* sp[9];
    const float* cp[9];
    for (int i = 0; i < 9; ++i) {
        sp[i] = (const float*)d_in[5 + i];
        cp[i] = (const float*)d_in[14 + i];
    }

    // workspace carve-up (floats)
    float* ws = (float*)d_ws;
    float* out0  = ws;               ws += (size_t)BB * DD * LL;        // 2.10M
    float* nrm   = ws;               ws += (size_t)BB * DD * LL;        // 2.10M
    float* xz    = ws;               ws += (size_t)BB * 2 * EE * LL;    // 8.39M
    float* xc    = ws;               ws += (size_t)BB * EE * LL;        // 4.19M
    float* xdbl  = ws;               ws += (size_t)BB * 48 * LL;        // 0.39M
    float* dtb   = ws;               ws += (size_t)BB * EE * LL;        // 4.19M
    float* yb    = ws;               ws += (size_t)BB * EE * LL;        // 4.19M
    float* soutb = ws;               ws += (size_t)BB * DD * LL;        // 2.10M
    float* coutb = ws;               ws += (size_t)BB * DD * LL;        // 2.10M
    float* aprod = ws;               ws += (size_t)NC * BB * EE * NN;   // 0.26M
    float* hendb = ws;               ws += (size_t)NC * BB * EE * NN;
    float* carry = ws;               ws += (size_t)NC * BB * EE * NN;

    // 1. conv_ff
    k_conv_ff<<<dim3(LL / 512, DD / 4, BB), 256, 0, stream>>>(x, ff_w, ff_b, out0);

    auto mamba = [&](const float* src, const float* const* P, float* outbuf) {
        // instance_norm(src) * mask -> nrm
        k_instnorm<<<dim3(BB * DD), 256, 0, stream>>>(src, mask, nrm);
        // in_proj: xz (B, 2E, L)
        k_gemm<0><<<dim3(LL / 64, 2 * EE / 64, BB), 256, 0, stream>>>(
            nrm, P[0], nullptr, xz, 2 * EE, DD, (long)DD * LL, (long)2 * EE * LL);
        // depthwise causal conv + silu -> xc (B, E, L)
        k_dwconv<<<dim3(LL / 256, EE, BB), 256, 0, stream>>>(xz, P[1], P[2], xc);
        // x_proj: xdbl (B, 48, L)
        k_gemm<0><<<dim3(LL / 64, 1, BB), 256, 0, stream>>>(
            xc, P[3], nullptr, xdbl, RR + 2 * NN, EE, (long)EE * LL, (long)48 * LL);
        // dt_proj + softplus: dtb (B, E, L)  (uses rows [0,R) of xdbl)
        k_gemm<1><<<dim3(LL / 64, EE / 64, BB), 256, 0, stream>>>(
            xdbl, P[4], P[5], dtb, EE, RR, (long)48 * LL, (long)EE * LL);
        // selective scan (chunked) fused with +u*D and *silu(z) -> yb
        k_scanA<<<dim3(NC * BB * EE * NN / 256), 256, 0, stream>>>(dtb, xc, xdbl, P[6], aprod, hendb);
        k_scanB<<<dim3(BB * EE * NN / 256), 256, 0, stream>>>(aprod, hendb, carry);
        k_scanC<<<dim3(NC * BB * EE * NN / 256), 256, 0, stream>>>(dtb, xc, xdbl, P[6], P[7], xz, carry, yb);
        // out_proj: outbuf (B, D, L)
        k_gemm<0><<<dim3(LL / 64, DD / 64, BB), 256, 0, stream>>>(
            yb, P[8], nullptr, outbuf, DD, EE, (long)EE * LL, (long)DD * LL);
    };

    mamba(out0, sp, soutb);   // self block on instance_norm(conv_ff(x))
    mamba(enc, cp, coutb);    // cross block on instance_norm(encoder_states)

    k_final<<<dim3((size_t)BB * DD * LL / 4 / 256), 256, 0, stream>>>(
        x, out0, soutb, coutb, mask, (float*)d_out);
}